// Round 3
// baseline (605.243 us; speedup 1.0000x reference)
//
#include <hip/hip_runtime.h>
#include <hip/hip_bf16.h>

#define BATCH 2048
#define IN_DIM 128
#define GRIDN 128
#define HID 256
#define DEPTH 7

typedef unsigned int u32;
typedef __attribute__((ext_vector_type(8))) short short8;
typedef __attribute__((ext_vector_type(4))) float floatx4;

// ---------------- ws layout (bytes) ----------------
#define OFF_FST   ((size_t)0)                     // bf16 fs_t [7][128][256][128]
#define SZ_FST    ((size_t)7*128*256*128*2)       // 58,720,256
#define OFF_ZT    (OFF_FST + SZ_FST)              // fp32 z_t [128][2048]  (transposed)
#define SZ_ZT     ((size_t)BATCH*IN_DIM*4)
#define OFF_HPRE  (OFF_ZT + SZ_ZT)                // fp32 h_pre [2048][256]
#define SZ_HPRE   ((size_t)BATCH*HID*4)
#define OFF_STATS (OFF_HPRE + SZ_HPRE)            // fp32 stats 3*[512]
#define SZ_STATS  ((size_t)3*2*HID*4)
#define OFF_KEYS  (OFF_STATS + SZ_STATS)          // u32 keys [256]
#define SZ_KEYS   ((size_t)256*4)
#define OFF_CW    (OFF_KEYS + SZ_KEYS)            // fp32 cw[7] (+pad)
#define SZ_CW     ((size_t)32)
#define OFF_Y1    (OFF_CW + SZ_CW)
#define SZ_Y      ((size_t)BATCH*HID*4)
#define OFF_Y2    (OFF_Y1 + SZ_Y)
#define OFF_Y3    (OFF_Y2 + SZ_Y)

__device__ __forceinline__ u32 pack2_bf16(float lo, float hi) {
  __hip_bfloat162 b2;
  b2.x = __float2bfloat16(lo);
  b2.y = __float2bfloat16(hi);
  return *reinterpret_cast<u32*>(&b2);
}

__device__ __forceinline__ float gelu_exact(float x) {
  return 0.5f * x * (1.0f + erff(x * 0.70710678118654752f));
}

// ---------------- prep1: coalesced per-feature min/max via monotone-key atomics
__global__ void prep1_kernel(const float* __restrict__ x, u32* __restrict__ keys) {
  int t = threadIdx.x;
  int base = blockIdx.x * 256 + t;
  float mn = 1e30f, mx = -1e30f;
#pragma unroll
  for (int j = 0; j < 16; ++j) {
    float v = x[base + j * 16384];   // 16384 % 128 == 0 -> same feature i each iter
    mn = fminf(mn, v); mx = fmaxf(mx, v);
  }
  __shared__ float smn[256], smx[256];
  smn[t] = mn; smx[t] = mx;
  __syncthreads();
  if (t < 128) {
    mn = fminf(smn[t], smn[t + 128]);
    mx = fmaxf(smx[t], smx[t + 128]);
    int i = base & 127;  // == t
    atomicMax(&keys[i], 0x7FFFFFFFu - __float_as_uint(mn));
    atomicMax(&keys[128 + i], __float_as_uint(mx));
  }
}

// ---------------- prep2: z_t[i][b] = (x[b][i]-mn)/(mx-mn+1e-6); cw on block 0
__global__ void prep2_kernel(const float* __restrict__ x, const u32* __restrict__ keys,
                             const float* __restrict__ depth_scores,
                             float* __restrict__ z_t, float* __restrict__ cw) {
  int t = threadIdx.x;
#pragma unroll
  for (int j = 0; j < 4; ++j) {
    int f = blockIdx.x * 1024 + j * 256 + t;
    int b = f >> 7, i = f & 127;
    float mnv = __uint_as_float(0x7FFFFFFFu - keys[i]);
    float mxv = __uint_as_float(keys[128 + i]);
    z_t[(size_t)i * BATCH + b] = (x[f] - mnv) * (1.0f / (mxv - mnv + 1e-6f));
  }
  if (blockIdx.x == 0 && t == 0) {
    float m = -1e30f;
    for (int d0 = 0; d0 < DEPTH; ++d0) m = fmaxf(m, depth_scores[d0]);
    float e[DEPTH]; float sum = 0.f;
    for (int d0 = 0; d0 < DEPTH; ++d0) { e[d0] = expf(depth_scores[d0] - m); sum += e[d0]; }
    float cacc = 0.f; float cs[DEPTH];
    for (int d0 = DEPTH - 1; d0 >= 0; --d0) { cacc += e[d0] / sum; cs[d0] = cacc; }
    for (int d0 = 0; d0 < DEPTH; ++d0) cw[d0] = cs[d0];
  }
}

// ---------------- fs fp32 [d,i,g,h] -> bf16 transposed [d,i,h,g], via LDS ----------------
__global__ void convert_kernel(const float* __restrict__ fs,
                               __hip_bfloat16* __restrict__ fs_t) {
  __shared__ u32 lds[256 * 33];   // [h][33] u32 rows: +1 pad -> conflict-free
  int slab = blockIdx.x;          // d*128 + i
  int t = threadIdx.x;
  const float* src = fs + (size_t)slab * (GRIDN * HID);
  char* dstb = (char*)(fs_t + (size_t)slab * (HID * GRIDN));

  for (int gh = 0; gh < 2; ++gh) {
    const float* s0 = src + (size_t)gh * 64 * HID + t;
#pragma unroll
    for (int g2 = 0; g2 < 32; ++g2) {
      float va = s0[(size_t)(2 * g2) * HID];
      float vb = s0[(size_t)(2 * g2 + 1) * HID];
      lds[t * 33 + g2] = pack2_bf16(va, vb);
    }
    __syncthreads();
#pragma unroll
    for (int it2 = 0; it2 < 8; ++it2) {
      int task = t + it2 * 256;      // [0,2048)
      int h = task >> 3, m = task & 7;
      u32 a0 = lds[h * 33 + m * 4 + 0];
      u32 a1 = lds[h * 33 + m * 4 + 1];
      u32 a2 = lds[h * 33 + m * 4 + 2];
      u32 a3 = lds[h * 33 + m * 4 + 3];
      *(uint4*)(dstb + (size_t)h * 256 + gh * 128 + m * 16) = make_uint4(a0, a1, a2, a3);
    }
    __syncthreads();
  }
}

// ---------------- big GEMM: h_pre += c_d * relu(z-grids) @ fs ----------------
// Barrier-free, LDS-free: A frags built in registers, B frags loaded
// global->register (one dwordx4 each). Wave tile 64x64, block = 4 waves
// M-stacked (share B stream via L1). Grid: 32 output tiles x 56 K-chunks
// (16 (d,i) slabs each) = 1792 blocks, XCD-swizzled so a chunk's 32 blocks
// share one XCD's L2 for the fs_t stream.
__launch_bounds__(256, 2)
__global__ void gemm_kernel(const float* __restrict__ z_t,
                            const float* __restrict__ grids,
                            const __hip_bfloat16* __restrict__ fs_t,
                            const float* __restrict__ cw,
                            float* __restrict__ h_pre) {
  int bx = blockIdx.x;
  int xcd = bx & 7;
  int j = bx >> 3;                  // [0,224)
  int chunk = xcd * 7 + (j >> 5);   // [0,56)
  int tile = j & 31;
  int mblk = tile >> 2;             // [0,8)
  int nblk = tile & 3;              // [0,4)
  int d = chunk >> 3;
  int ibase = (chunk & 7) * 16;

  int tid = threadIdx.x;
  int w = tid >> 6, l = tid & 63;
  int l15 = l & 15, l4 = l >> 4;

  int mbase = mblk * 256 + w * 64;
  int nbase = nblk * 64;

  floatx4 acc[4][4];
#pragma unroll
  for (int a = 0; a < 4; ++a)
#pragma unroll
    for (int b = 0; b < 4; ++b) acc[a][b] = (floatx4)0.f;

  const float* gbase = grids + ((size_t)d * IN_DIM + ibase) * GRIDN + l4 * 8;
  const __hip_bfloat16* bbase =
      fs_t + (size_t)(d * 128 + ibase) * (HID * GRIDN) + (size_t)(nbase + l15) * GRIDN + l4 * 8;
  const float* zbase = z_t + (size_t)ibase * BATCH + mbase + l15;

  for (int si = 0; si < 16; ++si) {
    float zv[4];
    zv[0] = zbase[(size_t)si * BATCH];
    zv[1] = zbase[(size_t)si * BATCH + 16];
    zv[2] = zbase[(size_t)si * BATCH + 32];
    zv[3] = zbase[(size_t)si * BATCH + 48];
    const float* gp = gbase + (size_t)si * GRIDN;
    const __hip_bfloat16* bp = bbase + (size_t)si * (HID * GRIDN);
#pragma unroll
    for (int ks = 0; ks < 4; ++ks) {
      float4 g0 = *(const float4*)(gp + ks * 32);
      float4 g1 = *(const float4*)(gp + ks * 32 + 4);
      short8 bf[4];
#pragma unroll
      for (int tt = 0; tt < 4; ++tt)
        bf[tt] = *(const short8*)(bp + ks * 32 + tt * 16 * GRIDN);
      short8 af[4];
#pragma unroll
      for (int u = 0; u < 4; ++u) {
        float zu = zv[u];
        union { uint4 q; short8 s; } pk;
        pk.q.x = pack2_bf16(fmaxf(zu - g0.x, 0.f), fmaxf(zu - g0.y, 0.f));
        pk.q.y = pack2_bf16(fmaxf(zu - g0.z, 0.f), fmaxf(zu - g0.w, 0.f));
        pk.q.z = pack2_bf16(fmaxf(zu - g1.x, 0.f), fmaxf(zu - g1.y, 0.f));
        pk.q.w = pack2_bf16(fmaxf(zu - g1.z, 0.f), fmaxf(zu - g1.w, 0.f));
        af[u] = pk.s;
      }
#pragma unroll
      for (int u = 0; u < 4; ++u)
#pragma unroll
        for (int tt = 0; tt < 4; ++tt)
          acc[u][tt] = __builtin_amdgcn_mfma_f32_16x16x32_bf16(af[u], bf[tt], acc[u][tt], 0, 0, 0);
    }
  }

  // epilogue: scale by c_d, atomic accumulate (C/D: col=l&15, row=(l>>4)*4+r)
  float cd = cw[d];
  int row0 = mbase + l4 * 4;
  int col0 = nbase + l15;
#pragma unroll
  for (int u = 0; u < 4; ++u) {
#pragma unroll
    for (int tt = 0; tt < 4; ++tt) {
      int col = col0 + tt * 16;
#pragma unroll
      for (int r = 0; r < 4; ++r) {
        int row = row0 + u * 16 + r;
        atomicAdd(&h_pre[(size_t)row * HID + col], cd * acc[u][tt][r]);
      }
    }
  }
}

// ---------------- MLP layer: Y = act(X) @ W + b, col stats of Y ----------------
template <int FIRST>
__global__ void mlp_kernel(const float* __restrict__ Xin,
                           const float* __restrict__ statsIn,
                           const float* __restrict__ gamma,
                           const float* __restrict__ beta,
                           const float* __restrict__ W,
                           const float* __restrict__ bias,
                           float* __restrict__ Yout,
                           float* __restrict__ statsOut) {
  __shared__ float Xs[4][HID];
  int br = blockIdx.x, c = threadIdx.x;
  float mean = 0.f, rstd = 1.f, gm = 1.f, bt = 0.f;
  if (!FIRST) {
    float s1 = statsIn[c], s2 = statsIn[HID + c];
    mean = s1 * (1.0f / BATCH);
    float var = s2 * (1.0f / BATCH) - mean * mean;
    rstd = rsqrtf(var + 1e-5f);
    gm = gamma[c]; bt = beta[c];
  }
#pragma unroll
  for (int r = 0; r < 4; ++r) {
    float v = Xin[(size_t)(br * 4 + r) * HID + c];
    if (!FIRST) v = gelu_exact((v - mean) * rstd * gm + bt);
    Xs[r][c] = v;
  }
  __syncthreads();
  float acc[4] = {0, 0, 0, 0};
#pragma unroll 8
  for (int k = 0; k < HID; ++k) {
    float wv = W[(size_t)k * HID + c];
#pragma unroll
    for (int r = 0; r < 4; ++r) acc[r] += Xs[r][k] * wv;
  }
  float bb = bias[c];
  float s1 = 0.f, s2 = 0.f;
#pragma unroll
  for (int r = 0; r < 4; ++r) {
    float y = acc[r] + bb;
    Yout[(size_t)(br * 4 + r) * HID + c] = y;
    s1 += y; s2 += y * y;
  }
  atomicAdd(&statsOut[c], s1);
  atomicAdd(&statsOut[HID + c], s2);
}

// ---------------- final: out = gelu(bn(Y3)) @ W_out + b_out ----------------
__global__ void final_kernel(const float* __restrict__ Y3,
                             const float* __restrict__ statsIn,
                             const float* __restrict__ gamma,
                             const float* __restrict__ beta,
                             const float* __restrict__ W_out,
                             const float* __restrict__ b_out,
                             float* __restrict__ out) {
  int w = threadIdx.x >> 6, l = threadIdx.x & 63;
  int b = blockIdx.x * 4 + w;
  float4 y = *(const float4*)(Y3 + (size_t)b * HID + l * 4);
  float4 wv = *(const float4*)(W_out + l * 4);
  float r4[4] = {y.x, y.y, y.z, y.w};
  float w4[4] = {wv.x, wv.y, wv.z, wv.w};
  float s = 0.f;
  int c0 = l * 4;
#pragma unroll
  for (int q = 0; q < 4; ++q) {
    int c = c0 + q;
    float s1 = statsIn[c], s2 = statsIn[HID + c];
    float mean = s1 * (1.0f / BATCH);
    float var = s2 * (1.0f / BATCH) - mean * mean;
    float rstd = rsqrtf(var + 1e-5f);
    float v = gelu_exact((r4[q] - mean) * rstd * gamma[c] + beta[c]);
    s += v * w4[q];
  }
#pragma unroll
  for (int off = 32; off > 0; off >>= 1) s += __shfl_down(s, off);
  if (l == 0) out[b] = s + b_out[0];
}

extern "C" void kernel_launch(void* const* d_in, const int* in_sizes, int n_in,
                              void* d_out, int out_size, void* d_ws, size_t ws_size,
                              hipStream_t stream) {
  const float* x      = (const float*)d_in[0];
  const float* grids  = (const float*)d_in[1];
  const float* fs     = (const float*)d_in[2];
  const float* dscore = (const float*)d_in[3];
  const float* mlp_W  = (const float*)d_in[4];
  const float* mlp_b  = (const float*)d_in[5];
  const float* bn_g   = (const float*)d_in[6];
  const float* bn_b   = (const float*)d_in[7];
  const float* W_out  = (const float*)d_in[8];
  const float* b_out  = (const float*)d_in[9];
  float* out = (float*)d_out;

  char* ws = (char*)d_ws;
  __hip_bfloat16* fs_t = (__hip_bfloat16*)(ws + OFF_FST);
  float* z_t   = (float*)(ws + OFF_ZT);
  float* h_pre = (float*)(ws + OFF_HPRE);
  float* stats = (float*)(ws + OFF_STATS);
  u32*   keys  = (u32*)(ws + OFF_KEYS);
  float* cw    = (float*)(ws + OFF_CW);
  float* Y1    = (float*)(ws + OFF_Y1);
  float* Y2    = (float*)(ws + OFF_Y2);
  float* Y3    = (float*)(ws + OFF_Y3);

  // zero the atomic accumulators (h_pre + BN stats + minmax keys)
  hipMemsetAsync(h_pre, 0, SZ_HPRE + SZ_STATS + SZ_KEYS, stream);

  prep1_kernel<<<64, 256, 0, stream>>>(x, keys);
  prep2_kernel<<<256, 256, 0, stream>>>(x, keys, dscore, z_t, cw);
  convert_kernel<<<DEPTH * IN_DIM, 256, 0, stream>>>(fs, fs_t);
  gemm_kernel<<<1792, 256, 0, stream>>>(z_t, grids, fs_t, cw, h_pre);

  mlp_kernel<1><<<512, 256, 0, stream>>>(h_pre, nullptr, nullptr, nullptr,
                                         mlp_W, mlp_b, Y1, stats);
  mlp_kernel<0><<<512, 256, 0, stream>>>(Y1, stats, bn_g, bn_b,
                                         mlp_W + 65536, mlp_b + 256, Y2, stats + 512);
  mlp_kernel<0><<<512, 256, 0, stream>>>(Y2, stats + 512, bn_g + 256, bn_b + 256,
                                         mlp_W + 2 * 65536, mlp_b + 2 * 256, Y3, stats + 1024);
  final_kernel<<<512, 256, 0, stream>>>(Y3, stats + 1024, bn_g + 512, bn_b + 512,
                                        W_out, b_out, out);
}

// Round 4
// 566.373 us; speedup vs baseline: 1.0686x; 1.0686x over previous
//
#include <hip/hip_runtime.h>
#include <hip/hip_bf16.h>

#define BATCH 2048
#define IN_DIM 128
#define GRIDN 128
#define HID 256
#define DEPTH 7

typedef unsigned int u32;
typedef __attribute__((ext_vector_type(8))) short short8;
typedef __attribute__((ext_vector_type(4))) float floatx4;

// ---------------- ws layout (bytes) ----------------
#define OFF_FST   ((size_t)0)                     // bf16 fs_t [7][128][256][128], pre-scaled by c_d
#define SZ_FST    ((size_t)7*128*256*128*2)       // 58,720,256
#define OFF_ZT    (OFF_FST + SZ_FST)              // fp32 z_t [128][2048]  (transposed)
#define SZ_ZT     ((size_t)BATCH*IN_DIM*4)
#define OFF_HPRE  (OFF_ZT + SZ_ZT)                // fp32 h_pre [2048][256]
#define SZ_HPRE   ((size_t)BATCH*HID*4)
#define OFF_STATS (OFF_HPRE + SZ_HPRE)            // fp32 stats 3*[512]
#define SZ_STATS  ((size_t)3*2*HID*4)
#define OFF_KEYS  (OFF_STATS + SZ_STATS)          // u32 keys [256]
#define SZ_KEYS   ((size_t)256*4)
#define OFF_CW    (OFF_KEYS + SZ_KEYS)            // fp32 cw[7] (+pad)
#define SZ_CW     ((size_t)32)
#define OFF_Y1    (OFF_CW + SZ_CW)
#define SZ_Y      ((size_t)BATCH*HID*4)
#define OFF_Y2    (OFF_Y1 + SZ_Y)
#define OFF_Y3    (OFF_Y2 + SZ_Y)

__device__ __forceinline__ u32 pack2_bf16(float lo, float hi) {
  __hip_bfloat162 b2;
  b2.x = __float2bfloat16(lo);
  b2.y = __float2bfloat16(hi);
  return *reinterpret_cast<u32*>(&b2);
}

__device__ __forceinline__ float gelu_exact(float x) {
  return 0.5f * x * (1.0f + erff(x * 0.70710678118654752f));
}

// ---------------- prep1: per-feature min/max via monotone-key atomics + cw
__global__ void prep1_kernel(const float* __restrict__ x, u32* __restrict__ keys,
                             const float* __restrict__ depth_scores,
                             float* __restrict__ cw) {
  int t = threadIdx.x;
  int base = blockIdx.x * 256 + t;
  float mn = 1e30f, mx = -1e30f;
#pragma unroll
  for (int j = 0; j < 16; ++j) {
    float v = x[base + j * 16384];   // 16384 % 128 == 0 -> same feature i each iter
    mn = fminf(mn, v); mx = fmaxf(mx, v);
  }
  __shared__ float smn[256], smx[256];
  smn[t] = mn; smx[t] = mx;
  __syncthreads();
  if (t < 128) {
    mn = fminf(smn[t], smn[t + 128]);
    mx = fmaxf(smx[t], smx[t + 128]);
    int i = base & 127;  // == t
    atomicMax(&keys[i], 0x7FFFFFFFu - __float_as_uint(mn));
    atomicMax(&keys[128 + i], __float_as_uint(mx));
  }
  if (blockIdx.x == 0 && t == 0) {
    float m = -1e30f;
    for (int d0 = 0; d0 < DEPTH; ++d0) m = fmaxf(m, depth_scores[d0]);
    float e[DEPTH]; float sum = 0.f;
    for (int d0 = 0; d0 < DEPTH; ++d0) { e[d0] = expf(depth_scores[d0] - m); sum += e[d0]; }
    float cacc = 0.f; float cs[DEPTH];
    for (int d0 = DEPTH - 1; d0 >= 0; --d0) { cacc += e[d0] / sum; cs[d0] = cacc; }
    for (int d0 = 0; d0 < DEPTH; ++d0) cw[d0] = cs[d0];
  }
}

// ---------------- prep2: z_t[i][b] = (x[b][i]-mn)/(mx-mn+1e-6)
__global__ void prep2_kernel(const float* __restrict__ x, const u32* __restrict__ keys,
                             float* __restrict__ z_t) {
  int t = threadIdx.x;
#pragma unroll
  for (int j = 0; j < 4; ++j) {
    int f = blockIdx.x * 1024 + j * 256 + t;
    int b = f >> 7, i = f & 127;
    float mnv = __uint_as_float(0x7FFFFFFFu - keys[i]);
    float mxv = __uint_as_float(keys[128 + i]);
    z_t[(size_t)i * BATCH + b] = (x[f] - mnv) * (1.0f / (mxv - mnv + 1e-6f));
  }
}

// ---------------- fs fp32 [d,i,g,h] -> c_d * bf16 transposed [d,i,h,g], via LDS
__global__ void convert_kernel(const float* __restrict__ fs,
                               const float* __restrict__ cw,
                               __hip_bfloat16* __restrict__ fs_t) {
  __shared__ u32 lds[256 * 33];   // [h][33] u32 rows: +1 pad -> conflict-free
  int slab = blockIdx.x;          // d*128 + i
  int t = threadIdx.x;
  float cd = cw[slab >> 7];
  const float* src = fs + (size_t)slab * (GRIDN * HID);
  char* dstb = (char*)(fs_t + (size_t)slab * (HID * GRIDN));

  for (int gh = 0; gh < 2; ++gh) {
    const float* s0 = src + (size_t)gh * 64 * HID + t;
#pragma unroll
    for (int g2 = 0; g2 < 32; ++g2) {
      float va = s0[(size_t)(2 * g2) * HID];
      float vb = s0[(size_t)(2 * g2 + 1) * HID];
      lds[t * 33 + g2] = pack2_bf16(cd * va, cd * vb);
    }
    __syncthreads();
#pragma unroll
    for (int it2 = 0; it2 < 8; ++it2) {
      int task = t + it2 * 256;      // [0,2048)
      int h = task >> 3, m = task & 7;
      u32 a0 = lds[h * 33 + m * 4 + 0];
      u32 a1 = lds[h * 33 + m * 4 + 1];
      u32 a2 = lds[h * 33 + m * 4 + 2];
      u32 a3 = lds[h * 33 + m * 4 + 3];
      *(uint4*)(dstb + (size_t)h * 256 + gh * 128 + m * 16) = make_uint4(a0, a1, a2, a3);
    }
    __syncthreads();
  }
}

// ---------------- big GEMM: h_pre += relu(z-grids) @ (c_d*fs) ----------------
// Block tile 256x256, 512 thr (8 waves, 2m x 4n, wave 128x64).
// A: VALU-generated into double-buffered LDS (NO vmem touches LDS ->
//    barriers drain lgkmcnt only; B/z/grid loads stay in flight across them).
// B: global->VGPR per wave (fs_t chunk is L2-resident via XCD swizzle).
// Grid: 8 mtiles x 64 K-chunks (14 (d,i)-slabs each) = 512 blocks = 2/CU.
__launch_bounds__(512, 2)
__global__ void gemm_kernel(const float* __restrict__ z_t,
                            const float* __restrict__ grids,
                            const __hip_bfloat16* __restrict__ fs_t,
                            float* __restrict__ h_pre) {
  __shared__ __align__(16) char lds[32768];   // 2 x 16KB A buffers

  int bx = blockIdx.x;
  int xcd = bx & 7;
  int idx = bx >> 3;                 // [0,64)
  int chunk = xcd * 8 + (idx & 7);   // [0,64) ; chunk's 8 mtile-blocks share an XCD
  int mtile = idx >> 3;              // [0,8)
  int slab0 = chunk * 14;            // linear (d,i) in [0,896)

  int tid = threadIdx.x;
  int w = tid >> 6, l = tid & 63;
  int l15 = l & 15, l4 = l >> 4;
  int wm = w >> 2;                   // 0..1  m-half (128 rows)
  int wn = w & 3;                    // 0..3  n-quarter (64 cols)
  int nbase = wn * 64;

  floatx4 acc[8][4];
#pragma unroll
  for (int a = 0; a < 8; ++a)
#pragma unroll
    for (int b = 0; b < 4; ++b) acc[a][b] = (floatx4)0.f;

  // producer rows for this thread (u = w*2+j): m = u*16 + l15
  int mrow0 = mtile * 256 + (w * 2 + 0) * 16 + l15;
  int mrow1 = mtile * 256 + (w * 2 + 1) * 16 + l15;

  // ---- generate A for step `st` into buffer `buf` (pure VALU + ds_write) ----
  auto gen = [&](int st, char* buf) {
    int slab = slab0 + (st >> 2);
    int ks = st & 3;
    int iz = slab & 127;
    float zv0 = z_t[(size_t)iz * BATCH + mrow0];
    float zv1 = z_t[(size_t)iz * BATCH + mrow1];
    const float* gp = grids + (size_t)slab * GRIDN + ks * 32 + l4 * 8;
    float4 g0 = *(const float4*)(gp);
    float4 g1 = *(const float4*)(gp + 4);
#pragma unroll
    for (int j = 0; j < 2; ++j) {
      float zv = j ? zv1 : zv0;
      uint4 pk;
      pk.x = pack2_bf16(fmaxf(zv - g0.x, 0.f), fmaxf(zv - g0.y, 0.f));
      pk.y = pack2_bf16(fmaxf(zv - g0.z, 0.f), fmaxf(zv - g0.w, 0.f));
      pk.z = pack2_bf16(fmaxf(zv - g1.x, 0.f), fmaxf(zv - g1.y, 0.f));
      pk.w = pack2_bf16(fmaxf(zv - g1.z, 0.f), fmaxf(zv - g1.w, 0.f));
      *(uint4*)(buf + (((w * 2 + j) * 64 + l) * 16)) = pk;
    }
  };

  gen(0, lds);
  __syncthreads();

  for (int st = 0; st < 56; ++st) {
    char* cur = lds + (st & 1) * 16384;
    char* nxt = lds + ((st + 1) & 1) * 16384;
    int slab = slab0 + (st >> 2);
    int ks = st & 3;

    // B frags: global -> VGPR (16B contiguous per lane along g)
    const __hip_bfloat16* bp =
        fs_t + (size_t)slab * (HID * GRIDN) + (size_t)(nbase + l15) * GRIDN + ks * 32 + l4 * 8;
    short8 bf[4];
#pragma unroll
    for (int tt = 0; tt < 4; ++tt)
      bf[tt] = *(const short8*)(bp + (size_t)tt * 16 * GRIDN);

    // A frags from LDS (this wave's m-half)
    short8 af[8];
#pragma unroll
    for (int u = 0; u < 8; ++u)
      af[u] = *(const short8*)(cur + (((wm * 8 + u) * 64 + l) * 16));

    // generate next step's A into the other buffer (safe: consumed 2 steps ago)
    int gs = (st + 1 < 56) ? st + 1 : st;
    gen(gs, nxt);

    // 32 MFMAs
#pragma unroll
    for (int u = 0; u < 8; ++u)
#pragma unroll
      for (int tt = 0; tt < 4; ++tt)
        acc[u][tt] = __builtin_amdgcn_mfma_f32_16x16x32_bf16(af[u], bf[tt], acc[u][tt], 0, 0, 0);

    __syncthreads();
  }

  // epilogue: atomic accumulate (C/D: col=l&15, row=(l>>4)*4+r)
  int row0 = mtile * 256 + wm * 128 + l4 * 4;
  int col0 = nbase + l15;
#pragma unroll
  for (int u = 0; u < 8; ++u) {
#pragma unroll
    for (int tt = 0; tt < 4; ++tt) {
      int col = col0 + tt * 16;
#pragma unroll
      for (int r = 0; r < 4; ++r) {
        int row = row0 + u * 16 + r;
        atomicAdd(&h_pre[(size_t)row * HID + col], acc[u][tt][r]);
      }
    }
  }
}

// ---------------- MLP layer: Y = act(X) @ W + b, col stats of Y ----------------
template <int FIRST>
__global__ void mlp_kernel(const float* __restrict__ Xin,
                           const float* __restrict__ statsIn,
                           const float* __restrict__ gamma,
                           const float* __restrict__ beta,
                           const float* __restrict__ W,
                           const float* __restrict__ bias,
                           float* __restrict__ Yout,
                           float* __restrict__ statsOut) {
  __shared__ float Xs[4][HID];
  int br = blockIdx.x, c = threadIdx.x;
  float mean = 0.f, rstd = 1.f, gm = 1.f, bt = 0.f;
  if (!FIRST) {
    float s1 = statsIn[c], s2 = statsIn[HID + c];
    mean = s1 * (1.0f / BATCH);
    float var = s2 * (1.0f / BATCH) - mean * mean;
    rstd = rsqrtf(var + 1e-5f);
    gm = gamma[c]; bt = beta[c];
  }
#pragma unroll
  for (int r = 0; r < 4; ++r) {
    float v = Xin[(size_t)(br * 4 + r) * HID + c];
    if (!FIRST) v = gelu_exact((v - mean) * rstd * gm + bt);
    Xs[r][c] = v;
  }
  __syncthreads();
  float acc[4] = {0, 0, 0, 0};
#pragma unroll 8
  for (int k = 0; k < HID; ++k) {
    float wv = W[(size_t)k * HID + c];
#pragma unroll
    for (int r = 0; r < 4; ++r) acc[r] += Xs[r][k] * wv;
  }
  float bb = bias[c];
  float s1 = 0.f, s2 = 0.f;
#pragma unroll
  for (int r = 0; r < 4; ++r) {
    float y = acc[r] + bb;
    Yout[(size_t)(br * 4 + r) * HID + c] = y;
    s1 += y; s2 += y * y;
  }
  atomicAdd(&statsOut[c], s1);
  atomicAdd(&statsOut[HID + c], s2);
}

// ---------------- final: out = gelu(bn(Y3)) @ W_out + b_out ----------------
__global__ void final_kernel(const float* __restrict__ Y3,
                             const float* __restrict__ statsIn,
                             const float* __restrict__ gamma,
                             const float* __restrict__ beta,
                             const float* __restrict__ W_out,
                             const float* __restrict__ b_out,
                             float* __restrict__ out) {
  int w = threadIdx.x >> 6, l = threadIdx.x & 63;
  int b = blockIdx.x * 4 + w;
  float4 y = *(const float4*)(Y3 + (size_t)b * HID + l * 4);
  float4 wv = *(const float4*)(W_out + l * 4);
  float r4[4] = {y.x, y.y, y.z, y.w};
  float w4[4] = {wv.x, wv.y, wv.z, wv.w};
  float s = 0.f;
  int c0 = l * 4;
#pragma unroll
  for (int q = 0; q < 4; ++q) {
    int c = c0 + q;
    float s1 = statsIn[c], s2 = statsIn[HID + c];
    float mean = s1 * (1.0f / BATCH);
    float var = s2 * (1.0f / BATCH) - mean * mean;
    float rstd = rsqrtf(var + 1e-5f);
    float v = gelu_exact((r4[q] - mean) * rstd * gamma[c] + beta[c]);
    s += v * w4[q];
  }
#pragma unroll
  for (int off = 32; off > 0; off >>= 1) s += __shfl_down(s, off);
  if (l == 0) out[b] = s + b_out[0];
}

extern "C" void kernel_launch(void* const* d_in, const int* in_sizes, int n_in,
                              void* d_out, int out_size, void* d_ws, size_t ws_size,
                              hipStream_t stream) {
  const float* x      = (const float*)d_in[0];
  const float* grids  = (const float*)d_in[1];
  const float* fs     = (const float*)d_in[2];
  const float* dscore = (const float*)d_in[3];
  const float* mlp_W  = (const float*)d_in[4];
  const float* mlp_b  = (const float*)d_in[5];
  const float* bn_g   = (const float*)d_in[6];
  const float* bn_b   = (const float*)d_in[7];
  const float* W_out  = (const float*)d_in[8];
  const float* b_out  = (const float*)d_in[9];
  float* out = (float*)d_out;

  char* ws = (char*)d_ws;
  __hip_bfloat16* fs_t = (__hip_bfloat16*)(ws + OFF_FST);
  float* z_t   = (float*)(ws + OFF_ZT);
  float* h_pre = (float*)(ws + OFF_HPRE);
  float* stats = (float*)(ws + OFF_STATS);
  u32*   keys  = (u32*)(ws + OFF_KEYS);
  float* cw    = (float*)(ws + OFF_CW);
  float* Y1    = (float*)(ws + OFF_Y1);
  float* Y2    = (float*)(ws + OFF_Y2);
  float* Y3    = (float*)(ws + OFF_Y3);

  // zero the atomic accumulators (h_pre + BN stats + minmax keys)
  hipMemsetAsync(h_pre, 0, SZ_HPRE + SZ_STATS + SZ_KEYS, stream);

  prep1_kernel<<<64, 256, 0, stream>>>(x, keys, dscore, cw);
  prep2_kernel<<<256, 256, 0, stream>>>(x, keys, z_t);
  convert_kernel<<<DEPTH * IN_DIM, 256, 0, stream>>>(fs, cw, fs_t);
  gemm_kernel<<<512, 512, 0, stream>>>(z_t, grids, fs_t, h_pre);

  mlp_kernel<1><<<512, 256, 0, stream>>>(h_pre, nullptr, nullptr, nullptr,
                                         mlp_W, mlp_b, Y1, stats);
  mlp_kernel<0><<<512, 256, 0, stream>>>(Y1, stats, bn_g, bn_b,
                                         mlp_W + 65536, mlp_b + 256, Y2, stats + 512);
  mlp_kernel<0><<<512, 256, 0, stream>>>(Y2, stats + 512, bn_g + 256, bn_b + 256,
                                         mlp_W + 2 * 65536, mlp_b + 2 * 256, Y3, stats + 1024);
  final_kernel<<<512, 256, 0, stream>>>(Y3, stats + 1024, bn_g + 512, bn_b + 512,
                                        W_out, b_out, out);
}

// Round 5
// 561.582 us; speedup vs baseline: 1.0777x; 1.0085x over previous
//
#include <hip/hip_runtime.h>
#include <hip/hip_bf16.h>

#define BATCH 2048
#define IN_DIM 128
#define GRIDN 128
#define HID 256
#define DEPTH 7

typedef unsigned int u32;
typedef __attribute__((ext_vector_type(8))) short short8;
typedef __attribute__((ext_vector_type(4))) float floatx4;

// ---------------- ws layout (bytes) ----------------
#define OFF_FST   ((size_t)0)                     // bf16 fs_t [7][128][256][128], pre-scaled by c_d
#define SZ_FST    ((size_t)7*128*256*128*2)       // 58,720,256
#define OFF_ZT    (OFF_FST + SZ_FST)              // fp32 z_t [128][2048]  (transposed)
#define SZ_ZT     ((size_t)BATCH*IN_DIM*4)
#define OFF_HPRE  (OFF_ZT + SZ_ZT)                // fp32 h_pre [2048][256]
#define SZ_HPRE   ((size_t)BATCH*HID*4)
#define OFF_STATS (OFF_HPRE + SZ_HPRE)            // fp32 stats 3*[512]
#define SZ_STATS  ((size_t)3*2*HID*4)
#define OFF_KEYS  (OFF_STATS + SZ_STATS)          // u32 keys [256]
#define SZ_KEYS   ((size_t)256*4)
#define OFF_CW    (OFF_KEYS + SZ_KEYS)            // fp32 cw[7] (+pad)
#define SZ_CW     ((size_t)32)
#define OFF_Y1    (OFF_CW + SZ_CW)
#define SZ_Y      ((size_t)BATCH*HID*4)
#define OFF_Y2    (OFF_Y1 + SZ_Y)
#define OFF_Y3    (OFF_Y2 + SZ_Y)

__device__ __forceinline__ u32 pack2_bf16(float lo, float hi) {
  __hip_bfloat162 b2;
  b2.x = __float2bfloat16(lo);
  b2.y = __float2bfloat16(hi);
  return *reinterpret_cast<u32*>(&b2);
}

// truncating bf16x2 pack: one v_perm_b32 (lo = hi16(a), hi = hi16(b))
__device__ __forceinline__ u32 pk_trunc(float a, float b) {
  return __builtin_amdgcn_perm(__float_as_uint(b), __float_as_uint(a), 0x07060302u);
}

__device__ __forceinline__ float gelu_exact(float x) {
  return 0.5f * x * (1.0f + erff(x * 0.70710678118654752f));
}

// ---------------- prep1: per-feature min/max via monotone-key atomics + cw
__global__ void prep1_kernel(const float* __restrict__ x, u32* __restrict__ keys,
                             const float* __restrict__ depth_scores,
                             float* __restrict__ cw) {
  int t = threadIdx.x;
  int base = blockIdx.x * 256 + t;
  float mn = 1e30f, mx = -1e30f;
#pragma unroll
  for (int j = 0; j < 16; ++j) {
    float v = x[base + j * 16384];   // 16384 % 128 == 0 -> same feature i each iter
    mn = fminf(mn, v); mx = fmaxf(mx, v);
  }
  __shared__ float smn[256], smx[256];
  smn[t] = mn; smx[t] = mx;
  __syncthreads();
  if (t < 128) {
    mn = fminf(smn[t], smn[t + 128]);
    mx = fmaxf(smx[t], smx[t + 128]);
    int i = base & 127;  // == t
    atomicMax(&keys[i], 0x7FFFFFFFu - __float_as_uint(mn));
    atomicMax(&keys[128 + i], __float_as_uint(mx));
  }
  if (blockIdx.x == 0 && t == 0) {
    float m = -1e30f;
    for (int d0 = 0; d0 < DEPTH; ++d0) m = fmaxf(m, depth_scores[d0]);
    float e[DEPTH]; float sum = 0.f;
    for (int d0 = 0; d0 < DEPTH; ++d0) { e[d0] = expf(depth_scores[d0] - m); sum += e[d0]; }
    float cacc = 0.f; float cs[DEPTH];
    for (int d0 = DEPTH - 1; d0 >= 0; --d0) { cacc += e[d0] / sum; cs[d0] = cacc; }
    for (int d0 = 0; d0 < DEPTH; ++d0) cw[d0] = cs[d0];
  }
}

// ---------------- prep2: z_t[i][b] via LDS transpose (256B contiguous stores)
// block: 64 batch rows x 128 features. grid = 32.
__global__ void prep2_kernel(const float* __restrict__ x, const u32* __restrict__ keys,
                             float* __restrict__ z_t) {
  __shared__ float lds[128 * 65];
  int t = threadIdx.x;
  int b0 = blockIdx.x * 64;
  // load 64x128 tile coalesced, store transposed into LDS (stride 65: conflict-free)
#pragma unroll
  for (int q = 0; q < 32; ++q) {
    int idx = q * 256 + t;              // [0, 8192)
    int b = idx >> 7, i = idx & 127;
    lds[i * 65 + b] = x[(size_t)(b0 + b) * IN_DIM + i];
  }
  __syncthreads();
  // write rows of z_t: 64 consecutive floats per wave = 256B segments
#pragma unroll
  for (int q = 0; q < 32; ++q) {
    int idx = q * 256 + t;
    int ii = idx >> 6, bb = idx & 63;
    float mnv = __uint_as_float(0x7FFFFFFFu - keys[ii]);
    float mxv = __uint_as_float(keys[128 + ii]);
    float v = (lds[ii * 65 + bb] - mnv) * (1.0f / (mxv - mnv + 1e-6f));
    z_t[(size_t)ii * BATCH + b0 + bb] = v;
  }
}

// ---------------- fs fp32 [d,i,g,h] -> c_d * bf16 transposed [d,i,h,g], via LDS
__global__ void convert_kernel(const float* __restrict__ fs,
                               const float* __restrict__ cw,
                               __hip_bfloat16* __restrict__ fs_t) {
  __shared__ u32 lds[256 * 33];   // [h][33] u32 rows: +1 pad -> conflict-free
  int slab = blockIdx.x;          // d*128 + i
  int t = threadIdx.x;
  float cd = cw[slab >> 7];
  const float* src = fs + (size_t)slab * (GRIDN * HID);
  char* dstb = (char*)(fs_t + (size_t)slab * (HID * GRIDN));

  for (int gh = 0; gh < 2; ++gh) {
    const float* s0 = src + (size_t)gh * 64 * HID + t;
#pragma unroll
    for (int g2 = 0; g2 < 32; ++g2) {
      float va = s0[(size_t)(2 * g2) * HID];
      float vb = s0[(size_t)(2 * g2 + 1) * HID];
      lds[t * 33 + g2] = pack2_bf16(cd * va, cd * vb);
    }
    __syncthreads();
#pragma unroll
    for (int it2 = 0; it2 < 8; ++it2) {
      int task = t + it2 * 256;      // [0,2048)
      int h = task >> 3, m = task & 7;
      u32 a0 = lds[h * 33 + m * 4 + 0];
      u32 a1 = lds[h * 33 + m * 4 + 1];
      u32 a2 = lds[h * 33 + m * 4 + 2];
      u32 a3 = lds[h * 33 + m * 4 + 3];
      *(uint4*)(dstb + (size_t)h * 256 + gh * 128 + m * 16) = make_uint4(a0, a1, a2, a3);
    }
    __syncthreads();
  }
}

// ---------------- big GEMM: h_pre += relu(z-grids) @ (c_d*fs) ----------------
// Barrier-free, LDS-free. Wave tile 64(M) x 128(N): A frags generated in
// registers (v_perm truncating pack), B frags global->VGPR dwordx4.
// 512 blocks x 256 thr (4 independent waves) = 2 blocks/CU, 2 waves/SIMD.
// K split 32 chunks x 28 slabs; chunk -> XCD via bx&7 so its 16 blocks share L2.
__launch_bounds__(256, 2)
__global__ void gemm_kernel(const float* __restrict__ z_t,
                            const float* __restrict__ grids,
                            const __hip_bfloat16* __restrict__ fs_t,
                            float* __restrict__ h_pre) {
  int bx = blockIdx.x;
  int xcd = bx & 7;
  int t6 = bx >> 3;                 // [0,64)
  int cg = t6 >> 4;                 // [0,4)
  int jb = t6 & 15;                 // [0,16)
  int chunk = xcd + 8 * cg;         // [0,32); chunk&7 == xcd -> same-XCD blocks
  int slab0 = chunk * 28;           // 28 (d,i) slabs per chunk

  int tid = threadIdx.x;
  int w = tid >> 6, l = tid & 63;
  int l15 = l & 15, l4 = l >> 4;

  int mtile = jb * 2 + (w >> 1);    // [0,32), 64 rows
  int nhalf = w & 1;                // [0,2), 128 cols
  int mbase = mtile * 64;
  int nbase = nhalf * 128;

  floatx4 acc[4][8];
#pragma unroll
  for (int a = 0; a < 4; ++a)
#pragma unroll
    for (int b = 0; b < 8; ++b) acc[a][b] = (floatx4)0.f;

  const float* gribase = grids + (size_t)slab0 * GRIDN + l4 * 8;
  const __hip_bfloat16* fsbase =
      fs_t + (size_t)slab0 * (HID * GRIDN) + (size_t)(nbase + l15) * GRIDN + l4 * 8;

#pragma unroll 1
  for (int s = 0; s < 28; ++s) {
    int slab = slab0 + s;
    int iz = slab & 127;
    const float* zp = z_t + (size_t)iz * BATCH + mbase + l15;
    float zv0 = zp[0];
    float zv1 = zp[16];
    float zv2 = zp[32];
    float zv3 = zp[48];
    const float* gp = gribase + (size_t)s * GRIDN;
    const __hip_bfloat16* bp = fsbase + (size_t)s * (HID * GRIDN);

#pragma unroll
    for (int ks = 0; ks < 4; ++ks) {
      float4 g0 = *(const float4*)(gp + ks * 32);
      float4 g1 = *(const float4*)(gp + ks * 32 + 4);
      short8 bf[8];
#pragma unroll
      for (int tt = 0; tt < 8; ++tt)
        bf[tt] = *(const short8*)(bp + ks * 32 + (size_t)tt * 16 * GRIDN);

      short8 af[4];
      float zv[4] = {zv0, zv1, zv2, zv3};
#pragma unroll
      for (int u = 0; u < 4; ++u) {
        float zu = zv[u];
        union { uint4 q; short8 s8; } pk;
        pk.q.x = pk_trunc(fmaxf(zu - g0.x, 0.f), fmaxf(zu - g0.y, 0.f));
        pk.q.y = pk_trunc(fmaxf(zu - g0.z, 0.f), fmaxf(zu - g0.w, 0.f));
        pk.q.z = pk_trunc(fmaxf(zu - g1.x, 0.f), fmaxf(zu - g1.y, 0.f));
        pk.q.w = pk_trunc(fmaxf(zu - g1.z, 0.f), fmaxf(zu - g1.w, 0.f));
        af[u] = pk.s8;
      }
#pragma unroll
      for (int u = 0; u < 4; ++u)
#pragma unroll
        for (int tt = 0; tt < 8; ++tt)
          acc[u][tt] = __builtin_amdgcn_mfma_f32_16x16x32_bf16(af[u], bf[tt], acc[u][tt], 0, 0, 0);
    }
  }

  // epilogue: atomic accumulate (C/D: col=l&15, row=(l>>4)*4+r)
  int row0 = mbase + l4 * 4;
  int col0 = nbase + l15;
#pragma unroll
  for (int u = 0; u < 4; ++u) {
#pragma unroll
    for (int tt = 0; tt < 8; ++tt) {
      int col = col0 + tt * 16;
#pragma unroll
      for (int r = 0; r < 4; ++r) {
        int row = row0 + u * 16 + r;
        atomicAdd(&h_pre[(size_t)row * HID + col], acc[u][tt][r]);
      }
    }
  }
}

// ---------------- MLP layer: Y = act(X) @ W + b, col stats of Y ----------------
template <int FIRST>
__global__ void mlp_kernel(const float* __restrict__ Xin,
                           const float* __restrict__ statsIn,
                           const float* __restrict__ gamma,
                           const float* __restrict__ beta,
                           const float* __restrict__ W,
                           const float* __restrict__ bias,
                           float* __restrict__ Yout,
                           float* __restrict__ statsOut) {
  __shared__ float Xs[4][HID];
  int br = blockIdx.x, c = threadIdx.x;
  float mean = 0.f, rstd = 1.f, gm = 1.f, bt = 0.f;
  if (!FIRST) {
    float s1 = statsIn[c], s2 = statsIn[HID + c];
    mean = s1 * (1.0f / BATCH);
    float var = s2 * (1.0f / BATCH) - mean * mean;
    rstd = rsqrtf(var + 1e-5f);
    gm = gamma[c]; bt = beta[c];
  }
#pragma unroll
  for (int r = 0; r < 4; ++r) {
    float v = Xin[(size_t)(br * 4 + r) * HID + c];
    if (!FIRST) v = gelu_exact((v - mean) * rstd * gm + bt);
    Xs[r][c] = v;
  }
  __syncthreads();
  float acc[4] = {0, 0, 0, 0};
#pragma unroll 8
  for (int k = 0; k < HID; ++k) {
    float wv = W[(size_t)k * HID + c];
#pragma unroll
    for (int r = 0; r < 4; ++r) acc[r] += Xs[r][k] * wv;
  }
  float bb = bias[c];
  float s1 = 0.f, s2 = 0.f;
#pragma unroll
  for (int r = 0; r < 4; ++r) {
    float y = acc[r] + bb;
    Yout[(size_t)(br * 4 + r) * HID + c] = y;
    s1 += y; s2 += y * y;
  }
  atomicAdd(&statsOut[c], s1);
  atomicAdd(&statsOut[HID + c], s2);
}

// ---------------- final: out = gelu(bn(Y3)) @ W_out + b_out ----------------
__global__ void final_kernel(const float* __restrict__ Y3,
                             const float* __restrict__ statsIn,
                             const float* __restrict__ gamma,
                             const float* __restrict__ beta,
                             const float* __restrict__ W_out,
                             const float* __restrict__ b_out,
                             float* __restrict__ out) {
  int w = threadIdx.x >> 6, l = threadIdx.x & 63;
  int b = blockIdx.x * 4 + w;
  float4 y = *(const float4*)(Y3 + (size_t)b * HID + l * 4);
  float4 wv = *(const float4*)(W_out + l * 4);
  float r4[4] = {y.x, y.y, y.z, y.w};
  float w4[4] = {wv.x, wv.y, wv.z, wv.w};
  float s = 0.f;
  int c0 = l * 4;
#pragma unroll
  for (int q = 0; q < 4; ++q) {
    int c = c0 + q;
    float s1 = statsIn[c], s2 = statsIn[HID + c];
    float mean = s1 * (1.0f / BATCH);
    float var = s2 * (1.0f / BATCH) - mean * mean;
    float rstd = rsqrtf(var + 1e-5f);
    float v = gelu_exact((r4[q] - mean) * rstd * gamma[c] + beta[c]);
    s += v * w4[q];
  }
#pragma unroll
  for (int off = 32; off > 0; off >>= 1) s += __shfl_down(s, off);
  if (l == 0) out[b] = s + b_out[0];
}

extern "C" void kernel_launch(void* const* d_in, const int* in_sizes, int n_in,
                              void* d_out, int out_size, void* d_ws, size_t ws_size,
                              hipStream_t stream) {
  const float* x      = (const float*)d_in[0];
  const float* grids  = (const float*)d_in[1];
  const float* fs     = (const float*)d_in[2];
  const float* dscore = (const float*)d_in[3];
  const float* mlp_W  = (const float*)d_in[4];
  const float* mlp_b  = (const float*)d_in[5];
  const float* bn_g   = (const float*)d_in[6];
  const float* bn_b   = (const float*)d_in[7];
  const float* W_out  = (const float*)d_in[8];
  const float* b_out  = (const float*)d_in[9];
  float* out = (float*)d_out;

  char* ws = (char*)d_ws;
  __hip_bfloat16* fs_t = (__hip_bfloat16*)(ws + OFF_FST);
  float* z_t   = (float*)(ws + OFF_ZT);
  float* h_pre = (float*)(ws + OFF_HPRE);
  float* stats = (float*)(ws + OFF_STATS);
  u32*   keys  = (u32*)(ws + OFF_KEYS);
  float* cw    = (float*)(ws + OFF_CW);
  float* Y1    = (float*)(ws + OFF_Y1);
  float* Y2    = (float*)(ws + OFF_Y2);
  float* Y3    = (float*)(ws + OFF_Y3);

  // zero the atomic accumulators (h_pre + BN stats + minmax keys)
  hipMemsetAsync(h_pre, 0, SZ_HPRE + SZ_STATS + SZ_KEYS, stream);

  prep1_kernel<<<64, 256, 0, stream>>>(x, keys, dscore, cw);
  prep2_kernel<<<32, 256, 0, stream>>>(x, keys, z_t);
  convert_kernel<<<DEPTH * IN_DIM, 256, 0, stream>>>(fs, cw, fs_t);
  gemm_kernel<<<512, 256, 0, stream>>>(z_t, grids, fs_t, h_pre);

  mlp_kernel<1><<<512, 256, 0, stream>>>(h_pre, nullptr, nullptr, nullptr,
                                         mlp_W, mlp_b, Y1, stats);
  mlp_kernel<0><<<512, 256, 0, stream>>>(Y1, stats, bn_g, bn_b,
                                         mlp_W + 65536, mlp_b + 256, Y2, stats + 512);
  mlp_kernel<0><<<512, 256, 0, stream>>>(Y2, stats + 512, bn_g + 256, bn_b + 256,
                                         mlp_W + 2 * 65536, mlp_b + 2 * 256, Y3, stats + 1024);
  final_kernel<<<512, 256, 0, stream>>>(Y3, stats + 1024, bn_g + 512, bn_b + 512,
                                        W_out, b_out, out);
}

// Round 6
// 450.554 us; speedup vs baseline: 1.3433x; 1.2464x over previous
//
#include <hip/hip_runtime.h>
#include <hip/hip_bf16.h>

#define BATCH 2048
#define IN_DIM 128
#define GRIDN 128
#define HID 256
#define DEPTH 7

typedef unsigned int u32;
typedef __attribute__((ext_vector_type(8))) short short8;
typedef __attribute__((ext_vector_type(4))) float floatx4;

// ---------------- ws layout (bytes) ----------------
// fs2: bf16, MFMA-frag-ordered: [slab:896][nhalf:2][ks:4][tt:8][l4:4][l15:16][g8:8]
#define OFF_FST   ((size_t)0)
#define SZ_FST    ((size_t)7*128*256*128*2)       // 58,720,256
#define OFF_ZT    (OFF_FST + SZ_FST)              // fp32 z_t [128][2048]
#define SZ_ZT     ((size_t)BATCH*IN_DIM*4)
#define OFF_HPRE  (OFF_ZT + SZ_ZT)                // fp32 h_pre [2048][256]
#define SZ_HPRE   ((size_t)BATCH*HID*4)
#define OFF_STATS (OFF_HPRE + SZ_HPRE)            // fp32 stats 3*[512]
#define SZ_STATS  ((size_t)3*2*HID*4)
#define OFF_KEYS  (OFF_STATS + SZ_STATS)          // u32 keys [256]
#define SZ_KEYS   ((size_t)256*4)
#define OFF_CW    (OFF_KEYS + SZ_KEYS)            // fp32 cw[7] (+pad)
#define SZ_CW     ((size_t)32)
#define OFF_Y1    (OFF_CW + SZ_CW)
#define SZ_Y      ((size_t)BATCH*HID*4)
#define OFF_Y2    (OFF_Y1 + SZ_Y)
#define OFF_Y3    (OFF_Y2 + SZ_Y)

__device__ __forceinline__ void gload_lds16(const void* g, void* l) {
  __builtin_amdgcn_global_load_lds(
      (const __attribute__((address_space(1))) u32*)g,
      (__attribute__((address_space(3))) u32*)l, 16, 0, 0);
}

__device__ __forceinline__ u32 pack2_bf16(float lo, float hi) {
  __hip_bfloat162 b2;
  b2.x = __float2bfloat16(lo);
  b2.y = __float2bfloat16(hi);
  return *reinterpret_cast<u32*>(&b2);
}

// truncating bf16x2 pack: one v_perm_b32 (lo = hi16(a), hi = hi16(b))
__device__ __forceinline__ u32 pk_trunc(float a, float b) {
  return __builtin_amdgcn_perm(__float_as_uint(b), __float_as_uint(a), 0x07060302u);
}

__device__ __forceinline__ float gelu_exact(float x) {
  return 0.5f * x * (1.0f + erff(x * 0.70710678118654752f));
}

// ---------------- prep1: per-feature min/max via monotone-key atomics + cw
__global__ void prep1_kernel(const float* __restrict__ x, u32* __restrict__ keys,
                             const float* __restrict__ depth_scores,
                             float* __restrict__ cw) {
  int t = threadIdx.x;
  int base = blockIdx.x * 256 + t;
  float mn = 1e30f, mx = -1e30f;
#pragma unroll
  for (int j = 0; j < 16; ++j) {
    float v = x[base + j * 16384];   // 16384 % 128 == 0 -> same feature i each iter
    mn = fminf(mn, v); mx = fmaxf(mx, v);
  }
  __shared__ float smn[256], smx[256];
  smn[t] = mn; smx[t] = mx;
  __syncthreads();
  if (t < 128) {
    mn = fminf(smn[t], smn[t + 128]);
    mx = fmaxf(smx[t], smx[t + 128]);
    int i = base & 127;  // == t
    atomicMax(&keys[i], 0x7FFFFFFFu - __float_as_uint(mn));
    atomicMax(&keys[128 + i], __float_as_uint(mx));
  }
  if (blockIdx.x == 0 && t == 0) {
    float m = -1e30f;
    for (int d0 = 0; d0 < DEPTH; ++d0) m = fmaxf(m, depth_scores[d0]);
    float e[DEPTH]; float sum = 0.f;
    for (int d0 = 0; d0 < DEPTH; ++d0) { e[d0] = expf(depth_scores[d0] - m); sum += e[d0]; }
    float cacc = 0.f; float cs[DEPTH];
    for (int d0 = DEPTH - 1; d0 >= 0; --d0) { cacc += e[d0] / sum; cs[d0] = cacc; }
    for (int d0 = 0; d0 < DEPTH; ++d0) cw[d0] = cs[d0];
  }
}

// ---------------- prep2: z_t[i][b] via LDS transpose (256B contiguous stores)
__global__ void prep2_kernel(const float* __restrict__ x, const u32* __restrict__ keys,
                             float* __restrict__ z_t) {
  __shared__ float lds[128 * 65];
  int t = threadIdx.x;
  int b0 = blockIdx.x * 64;
#pragma unroll
  for (int q = 0; q < 32; ++q) {
    int idx = q * 256 + t;              // [0, 8192)
    int b = idx >> 7, i = idx & 127;
    lds[i * 65 + b] = x[(size_t)(b0 + b) * IN_DIM + i];
  }
  __syncthreads();
#pragma unroll
  for (int q = 0; q < 32; ++q) {
    int idx = q * 256 + t;
    int ii = idx >> 6, bb = idx & 63;
    float mnv = __uint_as_float(0x7FFFFFFFu - keys[ii]);
    float mxv = __uint_as_float(keys[128 + ii]);
    float v = (lds[ii * 65 + bb] - mnv) * (1.0f / (mxv - mnv + 1e-6f));
    z_t[(size_t)ii * BATCH + b0 + bb] = v;
  }
}

// ---------------- fs fp32 [d,i,g,h] -> c_d*bf16, MFMA-frag-ordered fs2 ----------------
// fs2[slab][nhalf][ks][tt][l4][l15][g8]: element (h, g) with h = nhalf*128+tt*16+l15,
// g = ks*32 + l4*8 + g8. Each 1KB slot = one contiguous wave B-fragment.
__global__ void convert_kernel(const float* __restrict__ fs,
                               const float* __restrict__ cw,
                               __hip_bfloat16* __restrict__ fs2) {
  __shared__ u32 lds[256 * 33];   // [h][33] u32 rows: +1 pad
  int slab = blockIdx.x;          // d*128 + i
  int t = threadIdx.x;
  float cd = cw[slab >> 7];
  const float* src = fs + (size_t)slab * (GRIDN * HID);
  char* dstb = (char*)fs2 + (size_t)slab * 65536;

  for (int gh = 0; gh < 2; ++gh) {
    // phase 1: row h=t, read g coalesced (lanes over h), pack scaled bf16x2
    const float* s0 = src + (size_t)gh * 64 * HID + t;
#pragma unroll
    for (int g2 = 0; g2 < 32; ++g2) {
      float va = s0[(size_t)(2 * g2) * HID];
      float vb = s0[(size_t)(2 * g2 + 1) * HID];
      lds[t * 33 + g2] = pack2_bf16(cd * va, cd * vb);
    }
    __syncthreads();
    // phase 2: emit frag-ordered 16B chunks, lanes contiguous in dst
#pragma unroll
    for (int it2 = 0; it2 < 8; ++it2) {
      int task = t + it2 * 256;         // [0,2048) = 32KB of this gh-half
      int c = task >> 9;                // [0,4): nhalf*2 + ksl
      int q = task & 511;
      int nhalf = c >> 1, ksl = c & 1;
      int tt = q >> 6, l4 = (q >> 4) & 3, l15 = q & 15;
      int h = nhalf * 128 + tt * 16 + l15;
      int m = ksl * 4 + l4;             // u32-group within this gh half
      u32 a0 = lds[h * 33 + m * 4 + 0];
      u32 a1 = lds[h * 33 + m * 4 + 1];
      u32 a2 = lds[h * 33 + m * 4 + 2];
      u32 a3 = lds[h * 33 + m * 4 + 3];
      size_t off = (size_t)nhalf * 32768 + (size_t)(gh * 2 + ksl) * 8192 +
                   (size_t)tt * 1024 + l4 * 256 + l15 * 16;
      *(uint4*)(dstb + off) = make_uint4(a0, a1, a2, a3);
    }
    __syncthreads();
  }
}

// ---------------- big GEMM: h_pre += relu(z-grids) @ (c_d*fs) ----------------
// Barrier-free wave-private async pipeline:
//   - B staged per (s,ks) step via 8x global_load_lds (1KB contiguous each)
//     into this wave's 2x8KB LDS double buffer; explicit vmcnt(0) wait at
//     step top covers the batch issued one full step (~800 cyc) earlier.
//   - A generated in registers (pk_trunc), z/grids register-prefetched 1 step.
//   - ds_read_b128 frag reads are lane-contiguous -> conflict-free.
// Wave tile 64Mx128N; block 256 thr = 4 waves (2m x 2n) = 128x256 tile.
// Grid: 16 mtiles x 32 K-chunks (28 slabs) = 512 blocks = 2/CU, XCD-swizzled.
__launch_bounds__(256, 2)
__global__ void gemm_kernel(const float* __restrict__ z_t,
                            const float* __restrict__ grids,
                            const __hip_bfloat16* __restrict__ fs2,
                            float* __restrict__ h_pre) {
  __shared__ __align__(16) char lds[65536];   // 4 waves x 16KB (2x8KB dbuf)

  int bx = blockIdx.x;
  int xcd = bx & 7;
  int t6 = bx >> 3;                 // [0,64)
  int cg = t6 >> 4;                 // [0,4)
  int jb = t6 & 15;                 // [0,16) mtile(128)
  int chunk = xcd + 8 * cg;         // [0,32); same-XCD blocks share fs2 chunk
  int slab0 = chunk * 28;

  int tid = threadIdx.x;
  int w = tid >> 6, l = tid & 63;
  int l15 = l & 15, l4 = l >> 4;
  int wm = w >> 1;                  // m-half of block tile
  int wn = w & 1;                   // nhalf
  int mbase = jb * 128 + wm * 64;
  int nbase = wn * 128;
  char* mylds = lds + w * 16384;

  floatx4 acc[4][8];
#pragma unroll
  for (int a = 0; a < 4; ++a)
#pragma unroll
    for (int b = 0; b < 8; ++b) acc[a][b] = (floatx4)0.f;

  const char* fsb = (const char*)fs2 + (size_t)slab0 * 65536 + (size_t)wn * 32768 +
                    (size_t)l * 16;

  // stage B for step = (s,ks) into buffer p
  auto stage = [&](int step, int p) {
    const char* srcb = fsb + (size_t)(step >> 2) * 65536 + (size_t)(step & 3) * 8192;
    char* dst = mylds + p * 8192;
#pragma unroll
    for (int j = 0; j < 8; ++j)
      gload_lds16(srcb + j * 1024, dst + j * 1024);
  };

  float zv[2][4];
  float4 g0[2], g1[2];
  auto loadzg = [&](int step, int p) {
    int slab = slab0 + (step >> 2);
    int iz = slab & 127;
    const float* zp = z_t + (size_t)iz * BATCH + mbase + l15;
    zv[p][0] = zp[0]; zv[p][1] = zp[16]; zv[p][2] = zp[32]; zv[p][3] = zp[48];
    const float* gp = grids + (size_t)slab * GRIDN + (step & 3) * 32 + l4 * 8;
    g0[p] = *(const float4*)gp;
    g1[p] = *(const float4*)(gp + 4);
  };

  loadzg(0, 0);
  stage(0, 0);

#pragma unroll 2
  for (int step = 0; step < 112; ++step) {
    int p = step & 1;
    // wait for this step's B DMA (and this step's z/g regs), wave-local
    __builtin_amdgcn_s_waitcnt(0x0F70);   // vmcnt(0), lgkm/exp no-wait
    __asm__ volatile("" ::: "memory");

    short8 bf[8];
#pragma unroll
    for (int tt = 0; tt < 8; ++tt)
      bf[tt] = *(const short8*)(mylds + p * 8192 + tt * 1024 + l * 16);
    __asm__ volatile("" ::: "memory");

    if (step + 1 < 112) stage(step + 1, p ^ 1);

    // A fragments: relu(z - grid), truncating bf16 pack
    short8 af[4];
#pragma unroll
    for (int u = 0; u < 4; ++u) {
      float zu = zv[p][u];
      union { uint4 q; short8 s8; } pk;
      pk.q.x = pk_trunc(fmaxf(zu - g0[p].x, 0.f), fmaxf(zu - g0[p].y, 0.f));
      pk.q.y = pk_trunc(fmaxf(zu - g0[p].z, 0.f), fmaxf(zu - g0[p].w, 0.f));
      pk.q.z = pk_trunc(fmaxf(zu - g1[p].x, 0.f), fmaxf(zu - g1[p].y, 0.f));
      pk.q.w = pk_trunc(fmaxf(zu - g1[p].z, 0.f), fmaxf(zu - g1[p].w, 0.f));
      af[u] = pk.s8;
    }

    if (step + 1 < 112) loadzg(step + 1, p ^ 1);

#pragma unroll
    for (int u = 0; u < 4; ++u)
#pragma unroll
      for (int tt = 0; tt < 8; ++tt)
        acc[u][tt] = __builtin_amdgcn_mfma_f32_16x16x32_bf16(af[u], bf[tt], acc[u][tt], 0, 0, 0);
  }

  // epilogue: atomic accumulate (C/D: col=l&15, row=(l>>4)*4+r)
  int row0 = mbase + l4 * 4;
  int col0 = nbase + l15;
#pragma unroll
  for (int u = 0; u < 4; ++u) {
#pragma unroll
    for (int tt = 0; tt < 8; ++tt) {
      int col = col0 + tt * 16;
#pragma unroll
      for (int r = 0; r < 4; ++r) {
        int row = row0 + u * 16 + r;
        atomicAdd(&h_pre[(size_t)row * HID + col], acc[u][tt][r]);
      }
    }
  }
}

// ---------------- MLP layer: Y = act(X) @ W + b, col stats of Y ----------------
template <int FIRST>
__global__ void mlp_kernel(const float* __restrict__ Xin,
                           const float* __restrict__ statsIn,
                           const float* __restrict__ gamma,
                           const float* __restrict__ beta,
                           const float* __restrict__ W,
                           const float* __restrict__ bias,
                           float* __restrict__ Yout,
                           float* __restrict__ statsOut) {
  __shared__ float Xs[4][HID];
  int br = blockIdx.x, c = threadIdx.x;
  float mean = 0.f, rstd = 1.f, gm = 1.f, bt = 0.f;
  if (!FIRST) {
    float s1 = statsIn[c], s2 = statsIn[HID + c];
    mean = s1 * (1.0f / BATCH);
    float var = s2 * (1.0f / BATCH) - mean * mean;
    rstd = rsqrtf(var + 1e-5f);
    gm = gamma[c]; bt = beta[c];
  }
#pragma unroll
  for (int r = 0; r < 4; ++r) {
    float v = Xin[(size_t)(br * 4 + r) * HID + c];
    if (!FIRST) v = gelu_exact((v - mean) * rstd * gm + bt);
    Xs[r][c] = v;
  }
  __syncthreads();
  float acc[4] = {0, 0, 0, 0};
#pragma unroll 8
  for (int k = 0; k < HID; ++k) {
    float wv = W[(size_t)k * HID + c];
#pragma unroll
    for (int r = 0; r < 4; ++r) acc[r] += Xs[r][k] * wv;
  }
  float bb = bias[c];
  float s1 = 0.f, s2 = 0.f;
#pragma unroll
  for (int r = 0; r < 4; ++r) {
    float y = acc[r] + bb;
    Yout[(size_t)(br * 4 + r) * HID + c] = y;
    s1 += y; s2 += y * y;
  }
  atomicAdd(&statsOut[c], s1);
  atomicAdd(&statsOut[HID + c], s2);
}

// ---------------- final: out = gelu(bn(Y3)) @ W_out + b_out ----------------
__global__ void final_kernel(const float* __restrict__ Y3,
                             const float* __restrict__ statsIn,
                             const float* __restrict__ gamma,
                             const float* __restrict__ beta,
                             const float* __restrict__ W_out,
                             const float* __restrict__ b_out,
                             float* __restrict__ out) {
  int w = threadIdx.x >> 6, l = threadIdx.x & 63;
  int b = blockIdx.x * 4 + w;
  float4 y = *(const float4*)(Y3 + (size_t)b * HID + l * 4);
  float4 wv = *(const float4*)(W_out + l * 4);
  float r4[4] = {y.x, y.y, y.z, y.w};
  float w4[4] = {wv.x, wv.y, wv.z, wv.w};
  float s = 0.f;
  int c0 = l * 4;
#pragma unroll
  for (int q = 0; q < 4; ++q) {
    int c = c0 + q;
    float s1 = statsIn[c], s2 = statsIn[HID + c];
    float mean = s1 * (1.0f / BATCH);
    float var = s2 * (1.0f / BATCH) - mean * mean;
    float rstd = rsqrtf(var + 1e-5f);
    float v = gelu_exact((r4[q] - mean) * rstd * gamma[c] + beta[c]);
    s += v * w4[q];
  }
#pragma unroll
  for (int off = 32; off > 0; off >>= 1) s += __shfl_down(s, off);
  if (l == 0) out[b] = s + b_out[0];
}

extern "C" void kernel_launch(void* const* d_in, const int* in_sizes, int n_in,
                              void* d_out, int out_size, void* d_ws, size_t ws_size,
                              hipStream_t stream) {
  const float* x      = (const float*)d_in[0];
  const float* grids  = (const float*)d_in[1];
  const float* fs     = (const float*)d_in[2];
  const float* dscore = (const float*)d_in[3];
  const float* mlp_W  = (const float*)d_in[4];
  const float* mlp_b  = (const float*)d_in[5];
  const float* bn_g   = (const float*)d_in[6];
  const float* bn_b   = (const float*)d_in[7];
  const float* W_out  = (const float*)d_in[8];
  const float* b_out  = (const float*)d_in[9];
  float* out = (float*)d_out;

  char* ws = (char*)d_ws;
  __hip_bfloat16* fs2 = (__hip_bfloat16*)(ws + OFF_FST);
  float* z_t   = (float*)(ws + OFF_ZT);
  float* h_pre = (float*)(ws + OFF_HPRE);
  float* stats = (float*)(ws + OFF_STATS);
  u32*   keys  = (u32*)(ws + OFF_KEYS);
  float* cw    = (float*)(ws + OFF_CW);
  float* Y1    = (float*)(ws + OFF_Y1);
  float* Y2    = (float*)(ws + OFF_Y2);
  float* Y3    = (float*)(ws + OFF_Y3);

  // zero the atomic accumulators (h_pre + BN stats + minmax keys)
  hipMemsetAsync(h_pre, 0, SZ_HPRE + SZ_STATS + SZ_KEYS, stream);

  prep1_kernel<<<64, 256, 0, stream>>>(x, keys, dscore, cw);
  prep2_kernel<<<32, 256, 0, stream>>>(x, keys, z_t);
  convert_kernel<<<DEPTH * IN_DIM, 256, 0, stream>>>(fs, cw, fs2);
  gemm_kernel<<<512, 256, 0, stream>>>(z_t, grids, fs2, h_pre);

  mlp_kernel<1><<<512, 256, 0, stream>>>(h_pre, nullptr, nullptr, nullptr,
                                         mlp_W, mlp_b, Y1, stats);
  mlp_kernel<0><<<512, 256, 0, stream>>>(Y1, stats, bn_g, bn_b,
                                         mlp_W + 65536, mlp_b + 256, Y2, stats + 512);
  mlp_kernel<0><<<512, 256, 0, stream>>>(Y2, stats + 512, bn_g + 256, bn_b + 256,
                                         mlp_W + 2 * 65536, mlp_b + 2 * 256, Y3, stats + 1024);
  final_kernel<<<512, 256, 0, stream>>>(Y3, stats + 1024, bn_g + 512, bn_b + 512,
                                        W_out, b_out, out);
}